// Round 8
// baseline (491.820 us; speedup 1.0000x reference)
//
#include <hip/hip_runtime.h>
#include <hip/hip_bf16.h>

#define N_USERS   50000
#define N_ITEMS   50000
#define N_ENT     100000
#define NE        2000000
#define NNI       1000000
#define DD        64

#define PART_E    12500    // entity rows per XCD partition
#define PART_I    6250     // item/user rows per XCD partition
#define GROUP2    250      // rows per sort group
#define NG2_E     50       // groups per entity partition
#define NG2_M     25       // groups per item/user partition (per direction)
#define SCAP      5760     // per-group capacity (mean 5000, +10.7 sigma)

#define ECAP_E    262144   // per-XCD-bucket capacity, edges
#define ECAP_M    131072   // per-XCD-bucket capacity, mat
#define CHUNK     4096
#define CAPB      640      // L1 LDS per-bucket staging

// ---------------------------------------------------------------------------
// L1 bucket: edges -> 8 XCD-partition buckets (ballot-aggregated LDS count,
// coalesced flushes). val = tail | etype<<17.
// ---------------------------------------------------------------------------
__global__ __launch_bounds__(256) void bucket_edge_L1(
        const int* __restrict__ head, const int* __restrict__ tail,
        const int* __restrict__ etype,
        int* __restrict__ stK, int* __restrict__ stV, int* __restrict__ cur) {
    __shared__ int bufK[8][CAPB];
    __shared__ int bufV[8][CAPB];
    __shared__ int lcnt[8];
    __shared__ int gbase[8];
    const int tid = threadIdx.x;
    const int lane = tid & 63;
    for (int cs = blockIdx.x * CHUNK; cs < NE; cs += gridDim.x * CHUNK) {
        if (tid < 8) lcnt[tid] = 0;
        __syncthreads();
        const int ce = min(cs + CHUNK, NE);
        for (int i0 = cs; i0 < ce; i0 += 256) {
            const int i = i0 + tid;
            const bool valid = i < ce;
            int h = 0, v = 0, b = 8;
            if (valid) {
                h = __builtin_nontemporal_load(head + i);
                v = __builtin_nontemporal_load(tail + i) |
                    (__builtin_nontemporal_load(etype + i) << 17);
                b = h / PART_E;
            }
            unsigned long long m[8];
            #pragma unroll
            for (int k = 0; k < 8; ++k) m[k] = __ballot(b == k);
            int base8 = 0;
            if (lane < 8) base8 = atomicAdd(&lcnt[lane], (int)__popcll(m[lane]));
            if (valid) {
                const int mybase = __shfl(base8, b);
                const int pos = mybase + (int)__popcll(m[b] & ((1ull << lane) - 1ull));
                if (pos < CAPB) { bufK[b][pos] = h; bufV[b][pos] = v; }
                else {
                    const int gp = atomicAdd(&cur[b], 1);
                    stK[(size_t)b * ECAP_E + gp] = h;
                    stV[(size_t)b * ECAP_E + gp] = v;
                }
            }
        }
        __syncthreads();
        if (tid < 8) gbase[tid] = atomicAdd(&cur[tid], min(lcnt[tid], CAPB));
        __syncthreads();
        for (int b = 0; b < 8; ++b) {
            const int nf = min(lcnt[b], CAPB);
            int* dK = stK + (size_t)b * ECAP_E + gbase[b];
            int* dV = stV + (size_t)b * ECAP_E + gbase[b];
            for (int j = tid; j < nf; j += 256) { dK[j] = bufK[b][j]; dV[j] = bufV[b][j]; }
        }
        __syncthreads();
    }
}

// ---------------------------------------------------------------------------
// L1 bucket: mat entries both directions, packed (key<<16)|other.
// ---------------------------------------------------------------------------
__global__ __launch_bounds__(256) void bucket_mat_L1(
        const int* __restrict__ mrow, const int* __restrict__ mcol,
        int* __restrict__ stC, int* __restrict__ curC,
        int* __restrict__ stR, int* __restrict__ curR) {
    __shared__ int bufc[8][CAPB];
    __shared__ int bufr[8][CAPB];
    __shared__ int lc[8], lr[8], gc[8], gr[8];
    const int tid = threadIdx.x;
    const int lane = tid & 63;
    for (int cs = blockIdx.x * CHUNK; cs < NNI; cs += gridDim.x * CHUNK) {
        if (tid < 8) { lc[tid] = 0; lr[tid] = 0; }
        __syncthreads();
        const int ce = min(cs + CHUNK, NNI);
        for (int i0 = cs; i0 < ce; i0 += 256) {
            const int i = i0 + tid;
            const bool valid = i < ce;
            int r = 0, c = 0, bc = 8, br = 8;
            if (valid) {
                r = __builtin_nontemporal_load(mrow + i);
                c = __builtin_nontemporal_load(mcol + i);
                bc = c / PART_I;
                br = r / PART_I;
            }
            unsigned long long mc[8], mrr[8];
            #pragma unroll
            for (int k = 0; k < 8; ++k) { mc[k] = __ballot(bc == k); mrr[k] = __ballot(br == k); }
            int bc8 = 0, br8 = 0;
            if (lane < 8) {
                bc8 = atomicAdd(&lc[lane], (int)__popcll(mc[lane]));
                br8 = atomicAdd(&lr[lane], (int)__popcll(mrr[lane]));
            }
            if (valid) {
                const unsigned long long lt = (1ull << lane) - 1ull;
                int pos = __shfl(bc8, bc) + (int)__popcll(mc[bc] & lt);
                const int vc = (int)(((unsigned)c << 16) | (unsigned)r);
                if (pos < CAPB) bufc[bc][pos] = vc;
                else stC[(size_t)bc * ECAP_M + atomicAdd(&curC[bc], 1)] = vc;
                pos = __shfl(br8, br) + (int)__popcll(mrr[br] & lt);
                const int vr = (int)(((unsigned)r << 16) | (unsigned)c);
                if (pos < CAPB) bufr[br][pos] = vr;
                else stR[(size_t)br * ECAP_M + atomicAdd(&curR[br], 1)] = vr;
            }
        }
        __syncthreads();
        if (tid < 8)       gc[tid]     = atomicAdd(&curC[tid],     min(lc[tid],     CAPB));
        else if (tid < 16) gr[tid - 8] = atomicAdd(&curR[tid - 8], min(lr[tid - 8], CAPB));
        __syncthreads();
        for (int b = 0; b < 8; ++b) {
            int nf = min(lc[b], CAPB);
            int* d = stC + (size_t)b * ECAP_M + gc[b];
            for (int j = tid; j < nf; j += 256) d[j] = bufc[b][j];
            nf = min(lr[b], CAPB);
            d = stR + (size_t)b * ECAP_M + gr[b];
            for (int j = tid; j < nf; j += 256) d[j] = bufr[b][j];
        }
        __syncthreads();
    }
}

// ---------------------------------------------------------------------------
// Direct group sort (entity): one block per 250-row group. Streams its whole
// XCD partition bucket (L2-resident, PLAIN loads on purpose), filters its
// rows (~2%), LDS counting-sort, coalesced write + per-row beg/cnt.
// st2 entries: payload only (tail | etype<<17).
// ---------------------------------------------------------------------------
__global__ __launch_bounds__(256) void sort_entity_direct(
        const int* __restrict__ stK, const int* __restrict__ stV,
        const int* __restrict__ cur,
        int* __restrict__ st2, int* __restrict__ row_beg, int* __restrict__ row_cnt) {
    __shared__ int bufE[SCAP];
    __shared__ int sorted_s[SCAP];
    __shared__ int sc[256];
    __shared__ int curs[GROUP2];
    __shared__ int nbuf;
    const int p = blockIdx.x & 7;
    const int g = blockIdx.x >> 3;
    const int tid = threadIdx.x;
    if (tid == 0) nbuf = 0;
    sc[tid] = 0;
    __syncthreads();
    const int n = cur[p];
    const int* sK = stK + (size_t)p * ECAP_E;
    const int* sV = stV + (size_t)p * ECAP_E;
    const int rlo = p * PART_E + g * GROUP2;   // global row base of this group

    // filter pass: int4 streaming over keys; payload gathered only on match
    const int nv = n >> 2;
    const int4* sK4 = (const int4*)sK;
    for (int i = tid; i < nv; i += 256) {
        const int4 h4 = sK4[i];
        const int ib = i << 2;
        #pragma unroll
        for (int q = 0; q < 4; ++q) {
            const int h = (q == 0) ? h4.x : (q == 1) ? h4.y : (q == 2) ? h4.z : h4.w;
            const unsigned rig = (unsigned)(h - rlo);
            if (rig < GROUP2) {
                const int v = sV[ib + q];
                const int pos = atomicAdd(&nbuf, 1);
                if (pos < SCAP) bufE[pos] = v | ((int)rig << 22);
                atomicAdd(&sc[rig], 1);
            }
        }
    }
    for (int i = (nv << 2) + tid; i < n; i += 256) {
        const int h = sK[i];
        const unsigned rig = (unsigned)(h - rlo);
        if (rig < GROUP2) {
            const int v = sV[i];
            const int pos = atomicAdd(&nbuf, 1);
            if (pos < SCAP) bufE[pos] = v | ((int)rig << 22);
            atomicAdd(&sc[rig], 1);
        }
    }
    __syncthreads();
    // exclusive scan of per-row counts
    const int x = sc[tid];
    for (int d = 1; d < 256; d <<= 1) {
        const int v = (tid >= d) ? sc[tid - d] : 0;
        __syncthreads();
        sc[tid] += v;
        __syncthreads();
    }
    const int excl = sc[tid] - x;
    if (tid < GROUP2) {
        curs[tid] = excl;
        row_beg[rlo + tid] = blockIdx.x * SCAP + excl;
        row_cnt[rlo + tid] = x;
    }
    __syncthreads();
    // scatter into sorted order (strip rig)
    const int nb = min(nbuf, SCAP);
    for (int i = tid; i < nb; i += 256) {
        const int e = bufE[i];
        const int pos = atomicAdd(&curs[e >> 22], 1);
        sorted_s[pos] = e & 0x3FFFFF;
    }
    __syncthreads();
    int* dst = st2 + (size_t)blockIdx.x * SCAP;
    for (int i = tid; i < nb; i += 256) dst[i] = sorted_s[i];
}

// ---------------------------------------------------------------------------
// Direct group sort (mat, both directions in one launch).
// blocks [0,200): col-keyed -> stC2/beg_c/cnt_c; [200,400): row-keyed.
// st2 entries: payload only (16 bits).
// ---------------------------------------------------------------------------
__global__ __launch_bounds__(256) void sort_mat_direct(
        const int* __restrict__ stC, const int* __restrict__ curC,
        int* __restrict__ stC2, int* __restrict__ beg_c, int* __restrict__ cnt_c,
        const int* __restrict__ stR, const int* __restrict__ curR,
        int* __restrict__ stR2, int* __restrict__ beg_r, int* __restrict__ cnt_r) {
    __shared__ int bufE[SCAP];
    __shared__ int sorted_s[SCAP];
    __shared__ int sc[256];
    __shared__ int curs[GROUP2];
    __shared__ int nbuf;
    const int b = blockIdx.x;
    const int dir = (b >= 8 * NG2_M) ? 1 : 0;
    const int bb = dir ? b - 8 * NG2_M : b;
    const int p = bb & 7;
    const int g = bb >> 3;
    const int tid = threadIdx.x;
    if (tid == 0) nbuf = 0;
    sc[tid] = 0;
    __syncthreads();
    const int n = (dir ? curR : curC)[p];
    const int* src = (dir ? stR : stC) + (size_t)p * ECAP_M;
    int* dst = (dir ? stR2 : stC2) + (size_t)bb * SCAP;
    int* beg = dir ? beg_r : beg_c;
    int* cntt = dir ? cnt_r : cnt_c;
    const int rlo = p * PART_I + g * GROUP2;

    const int nv = n >> 2;
    const int4* s4 = (const int4*)src;
    for (int i = tid; i < nv; i += 256) {
        const int4 u4 = s4[i];
        #pragma unroll
        for (int q = 0; q < 4; ++q) {
            const unsigned u = (unsigned)((q == 0) ? u4.x : (q == 1) ? u4.y : (q == 2) ? u4.z : u4.w);
            const unsigned rig = (u >> 16) - (unsigned)rlo;
            if (rig < GROUP2) {
                const int pos = atomicAdd(&nbuf, 1);
                if (pos < SCAP) bufE[pos] = (int)(u & 0xFFFFu) | ((int)rig << 16);
                atomicAdd(&sc[rig], 1);
            }
        }
    }
    for (int i = (nv << 2) + tid; i < n; i += 256) {
        const unsigned u = (unsigned)src[i];
        const unsigned rig = (u >> 16) - (unsigned)rlo;
        if (rig < GROUP2) {
            const int pos = atomicAdd(&nbuf, 1);
            if (pos < SCAP) bufE[pos] = (int)(u & 0xFFFFu) | ((int)rig << 16);
            atomicAdd(&sc[rig], 1);
        }
    }
    __syncthreads();
    const int x = sc[tid];
    for (int d = 1; d < 256; d <<= 1) {
        const int v = (tid >= d) ? sc[tid - d] : 0;
        __syncthreads();
        sc[tid] += v;
        __syncthreads();
    }
    const int excl = sc[tid] - x;
    if (tid < GROUP2) {
        curs[tid] = excl;
        beg[rlo + tid] = bb * SCAP + excl;
        cntt[rlo + tid] = x;
    }
    __syncthreads();
    const int nb = min(nbuf, SCAP);
    for (int i = tid; i < nb; i += 256) {
        const int e = bufE[i];
        const int pos = atomicAdd(&curs[e >> 16], 1);
        sorted_s[pos] = e & 0xFFFF;
    }
    __syncthreads();
    for (int i = tid; i < nb; i += 256) dst[i] = sorted_s[i];
}

// ---------------------------------------------------------------------------
// Pull aggregations: one 64-lane wave per destination row; lane = feature dim.
// ---------------------------------------------------------------------------
__global__ void pull_entity_kernel(const float* __restrict__ ent,
                                   const float* __restrict__ wgt,
                                   const int* __restrict__ row_beg,
                                   const int* __restrict__ row_cnt,
                                   const int* __restrict__ ids,
                                   float* __restrict__ out) {
    const int lane = threadIdx.x & 63;
    const int wid = (blockIdx.x * blockDim.x + threadIdx.x) >> 6;
    if (wid >= N_ENT) return;
    const int beg = row_beg[wid], nc = row_cnt[wid];
    const int end = beg + nc;
    float acc = 0.f;
    for (int base = beg; base < end; base += 64) {
        const int k = base + lane;
        int v = 0;
        if (k < end) v = ids[k];
        const int nn = min(64, end - base);
        int kk = 0;
        for (; kk + 4 <= nn; kk += 4) {
            const int v0 = __shfl(v, kk),     v1 = __shfl(v, kk + 1);
            const int v2 = __shfl(v, kk + 2), v3 = __shfl(v, kk + 3);
            const float a0 = ent[(size_t)(v0 & 0x1FFFF) * DD + lane] * wgt[((v0 >> 17) & 31) * DD + lane];
            const float a1 = ent[(size_t)(v1 & 0x1FFFF) * DD + lane] * wgt[((v1 >> 17) & 31) * DD + lane];
            const float a2 = ent[(size_t)(v2 & 0x1FFFF) * DD + lane] * wgt[((v2 >> 17) & 31) * DD + lane];
            const float a3 = ent[(size_t)(v3 & 0x1FFFF) * DD + lane] * wgt[((v3 >> 17) & 31) * DD + lane];
            acc += a0 + a1 + a2 + a3;
        }
        for (; kk < nn; ++kk) {
            const int vv = __shfl(v, kk);
            acc += ent[(size_t)(vv & 0x1FFFF) * DD + lane] * wgt[((vv >> 17) & 31) * DD + lane];
        }
    }
    out[(size_t)wid * DD + lane] = acc / fmaxf((float)nc, 1.0f);
}

__global__ void pull_iu_kernel(const float* __restrict__ uemb,
                               const float* __restrict__ wgt,
                               const int* __restrict__ row_beg,
                               const int* __restrict__ row_cnt,
                               const int* __restrict__ ids,
                               float* __restrict__ iu_out) {
    const int lane = threadIdx.x & 63;
    const int wid = (blockIdx.x * blockDim.x + threadIdx.x) >> 6;
    if (wid >= N_ITEMS) return;
    const float w0 = wgt[lane];
    const int beg = row_beg[wid], nc = row_cnt[wid];
    const int end = beg + nc;
    float acc = 0.f;
    for (int base = beg; base < end; base += 64) {
        const int k = base + lane;
        int v = 0;
        if (k < end) v = ids[k];
        const int nn = min(64, end - base);
        int kk = 0;
        for (; kk + 4 <= nn; kk += 4) {
            const int v0 = __shfl(v, kk),     v1 = __shfl(v, kk + 1);
            const int v2 = __shfl(v, kk + 2), v3 = __shfl(v, kk + 3);
            acc += uemb[(size_t)v0 * DD + lane] + uemb[(size_t)v1 * DD + lane]
                 + uemb[(size_t)v2 * DD + lane] + uemb[(size_t)v3 * DD + lane];
        }
        for (; kk < nn; ++kk) {
            const int vv = __shfl(v, kk);
            acc += uemb[(size_t)vv * DD + lane];
        }
    }
    iu_out[(size_t)wid * DD + lane] = acc * w0 / fmaxf((float)nc, 1.0f);
}

__global__ void pull_user_kernel(const float* __restrict__ fus,
                                 const int* __restrict__ row_beg,
                                 const int* __restrict__ row_cnt,
                                 const int* __restrict__ ids,
                                 float* __restrict__ uout) {
    const int lane = threadIdx.x & 63;
    const int wid = (blockIdx.x * blockDim.x + threadIdx.x) >> 6;
    if (wid >= N_USERS) return;
    const int beg = row_beg[wid], nc = row_cnt[wid];
    const int end = beg + nc;
    float acc = 0.f;
    for (int base = beg; base < end; base += 64) {
        const int k = base + lane;
        int v = 0;
        if (k < end) v = ids[k];
        const int nn = min(64, end - base);
        int kk = 0;
        for (; kk + 4 <= nn; kk += 4) {
            const int v0 = __shfl(v, kk),     v1 = __shfl(v, kk + 1);
            const int v2 = __shfl(v, kk + 2), v3 = __shfl(v, kk + 3);
            acc += fus[(size_t)v0 * DD + lane] + fus[(size_t)v1 * DD + lane]
                 + fus[(size_t)v2 * DD + lane] + fus[(size_t)v3 * DD + lane];
        }
        for (; kk < nn; ++kk) {
            const int vv = __shfl(v, kk);
            acc += fus[(size_t)vv * DD + lane];
        }
    }
    uout[(size_t)wid * DD + lane] = acc;
}

// ---------------------------------------------------------------------------
// Gate + fusion, in place on d_out. 4 items / 256-thread block.
// ---------------------------------------------------------------------------
__global__ void gate_fusion_kernel(float* __restrict__ kg_fus,
                                   const float* __restrict__ iu,
                                   const float* __restrict__ g1,
                                   const float* __restrict__ g2) {
    __shared__ float G1[64 * 65];
    __shared__ float G2[64 * 65];
    __shared__ float xs1[4][64];
    __shared__ float xs2[4][64];

    const int tid = threadIdx.x;
    for (int i = tid; i < 64 * 64; i += 256) {
        const int r = i >> 6, c = i & 63;
        G1[r * 65 + c] = g1[i];
        G2[r * 65 + c] = g2[i];
    }

    const int il = tid >> 6;
    const int j = tid & 63;
    const int item = blockIdx.x * 4 + il;

    const float x1 = kg_fus[(size_t)item * DD + j];
    const float x2 = iu[(size_t)item * DD + j];
    xs1[il][j] = x1;
    xs2[il][j] = x2;
    __syncthreads();

    float s = 0.0f;
    #pragma unroll
    for (int k = 0; k < 64; ++k) {
        s += xs1[il][k] * G1[j * 65 + k];
        s += xs2[il][k] * G2[j * 65 + k];
    }
    const float gi = 1.0f / (1.0f + __expf(-s));
    kg_fus[(size_t)item * DD + j] = gi * x1 + (1.0f - gi) * x2;
}

extern "C" void kernel_launch(void* const* d_in, const int* in_sizes, int n_in,
                              void* d_out, int out_size, void* d_ws, size_t ws_size,
                              hipStream_t stream) {
    const float* entity_emb = (const float*)d_in[0];
    const float* user_emb   = (const float*)d_in[1];
    const int*   edge_index = (const int*)d_in[2];
    const int*   edge_type  = (const int*)d_in[3];
    const int*   mat_row    = (const int*)d_in[4];
    const int*   mat_col    = (const int*)d_in[5];
    const float* weight     = (const float*)d_in[7];
    const float* gate1_w    = (const float*)d_in[8];
    const float* gate2_w    = (const float*)d_in[9];

    float* out = (float*)d_out;
    float* out_fusion = out;                       // rows [0, 50000)
    float* out_entity = out;                       // rows [0, 100000)
    float* out_user   = out + (size_t)N_ENT * DD;  // temp i_u_agg, then user_agg

    // workspace (ints), peak 27.6 MB via phase-ordered aliasing (proven size):
    //  A: st_ek (L1 edges K)  -> later stC|stR   (after sort_entity_direct)
    //  B: st_ev (L1 edges V)  -> later stC2      (after sort_entity_direct)
    //  C: st2_e (sorted edge) -> later stR2      (after pull_entity)
    int* W      = (int*)d_ws;
    int* cur_e  = W + 0;         // 8
    int* cur_c  = W + 8;         // 8
    int* cur_r  = W + 16;        // 8   (pad to 2048)
    int* st_ek  = W + 2048;                    // 2,097,152
    int* st_ev  = W + 2048 + 2097152;          // 2,097,152
    int* st2_e  = W + 2048 + 2 * 2097152;      // 400*5760 = 2,304,000
    int* stC    = st_ek;                       // 1,048,576 (aliases A)
    int* stR    = st_ek + 1048576;             // 1,048,576 (aliases A)
    int* stC2   = st_ev;                       // 200*5760 = 1,152,000 (aliases B)
    int* stR2   = st2_e;                       // 1,152,000 (aliases C)
    int* tabs   = W + 2048 + 2 * 2097152 + 2304000;
    int* beg_e  = tabs;            // 100,000
    int* cnt_e  = tabs + 100000;   // 100,000
    int* beg_c  = tabs + 200000;   // 50,000
    int* cnt_c  = tabs + 250000;   // 50,000
    int* beg_r  = tabs + 300000;   // 50,000
    int* cnt_r  = tabs + 350000;   // 50,000  (end = 6,900,352 ints ~ 27.6 MB)

    const int* head = edge_index;
    const int* tail = edge_index + NE;

    // zero L1 cursors
    (void)hipMemsetAsync(W, 0, 2048 * sizeof(int), stream);

    // ---- entity chain ----
    bucket_edge_L1<<<512, 256, 0, stream>>>(head, tail, edge_type, st_ek, st_ev, cur_e);
    sort_entity_direct<<<8 * NG2_E, 256, 0, stream>>>(st_ek, st_ev, cur_e,
                                                      st2_e, beg_e, cnt_e);
    pull_entity_kernel<<<N_ENT / 4, 256, 0, stream>>>(entity_emb, weight,
                                                      beg_e, cnt_e, st2_e, out_entity);

    // ---- mat chains (A/B/C recycled; must follow pull_entity) ----
    bucket_mat_L1<<<256, 256, 0, stream>>>(mat_row, mat_col, stC, cur_c, stR, cur_r);
    sort_mat_direct<<<16 * NG2_M, 256, 0, stream>>>(stC, cur_c, stC2, beg_c, cnt_c,
                                                    stR, cur_r, stR2, beg_r, cnt_r);
    pull_iu_kernel<<<N_ITEMS / 4, 256, 0, stream>>>(user_emb, weight,
                                                    beg_c, cnt_c, stC2, out_user);

    // ---- gate + fusion (in place on d_out item rows) ----
    gate_fusion_kernel<<<N_ITEMS / 4, 256, 0, stream>>>(out_fusion, out_user,
                                                        gate1_w, gate2_w);

    // ---- user_agg ----
    pull_user_kernel<<<N_USERS / 4, 256, 0, stream>>>(out_fusion,
                                                      beg_r, cnt_r, stR2, out_user);
}

// Round 12
// 378.545 us; speedup vs baseline: 1.2992x; 1.2992x over previous
//
#include <hip/hip_runtime.h>
#include <hip/hip_bf16.h>

#define N_USERS   50000
#define N_ITEMS   50000
#define N_ENT     100000
#define NE        2000000
#define NNI       1000000
#define DD        64

#define PART_E    12500    // entity rows per XCD partition
#define PART_I    6250     // item/user rows per XCD partition
#define GROUP     125      // rows per sort group
#define NG_E      100      // groups per entity partition
#define NG_M      50       // groups per item/user partition

#define ECAP_E    262144   // per-XCD-bucket capacity, edges (mean 250000)
#define ECAP_M    131072   // per-XCD-bucket capacity, mat   (mean 125000)
#define ST2CAP    2880     // per-group capacity (mean 2500)
#define CHUNK     4096
#define CAPB      640      // L1 LDS per-bucket staging
#define GCAP      96       // L2 LDS per-group staging

// ---------------------------------------------------------------------------
// L1 bucket: edges -> 8 XCD-partition buckets (ballot-aggregated LDS count,
// coalesced flushes). val = tail | etype<<17.
// ---------------------------------------------------------------------------
__global__ __launch_bounds__(256) void bucket_edge_L1(
        const int* __restrict__ head, const int* __restrict__ tail,
        const int* __restrict__ etype,
        int* __restrict__ stK, int* __restrict__ stV, int* __restrict__ cur) {
    __shared__ int bufK[8][CAPB];
    __shared__ int bufV[8][CAPB];
    __shared__ int lcnt[8];
    __shared__ int gbase[8];
    const int tid = threadIdx.x;
    const int lane = tid & 63;
    for (int cs = blockIdx.x * CHUNK; cs < NE; cs += gridDim.x * CHUNK) {
        if (tid < 8) lcnt[tid] = 0;
        __syncthreads();
        const int ce = min(cs + CHUNK, NE);
        for (int i0 = cs; i0 < ce; i0 += 256) {
            const int i = i0 + tid;
            const bool valid = i < ce;
            int h = 0, v = 0, b = 8;
            if (valid) {
                h = __builtin_nontemporal_load(head + i);
                v = __builtin_nontemporal_load(tail + i) |
                    (__builtin_nontemporal_load(etype + i) << 17);
                b = h / PART_E;
            }
            unsigned long long m[8];
            #pragma unroll
            for (int k = 0; k < 8; ++k) m[k] = __ballot(b == k);
            int base8 = 0;
            if (lane < 8) base8 = atomicAdd(&lcnt[lane], (int)__popcll(m[lane]));
            if (valid) {
                const int mybase = __shfl(base8, b);
                const int pos = mybase + (int)__popcll(m[b] & ((1ull << lane) - 1ull));
                if (pos < CAPB) { bufK[b][pos] = h; bufV[b][pos] = v; }
                else {
                    const int gp = atomicAdd(&cur[b], 1);
                    stK[(size_t)b * ECAP_E + gp] = h;
                    stV[(size_t)b * ECAP_E + gp] = v;
                }
            }
        }
        __syncthreads();
        if (tid < 8) gbase[tid] = atomicAdd(&cur[tid], min(lcnt[tid], CAPB));
        __syncthreads();
        for (int b = 0; b < 8; ++b) {
            const int nf = min(lcnt[b], CAPB);
            int* dK = stK + (size_t)b * ECAP_E + gbase[b];
            int* dV = stV + (size_t)b * ECAP_E + gbase[b];
            for (int j = tid; j < nf; j += 256) { dK[j] = bufK[b][j]; dV[j] = bufV[b][j]; }
        }
        __syncthreads();
    }
}

// ---------------------------------------------------------------------------
// L1 bucket: mat entries both directions, packed (key<<16)|other.
// ---------------------------------------------------------------------------
__global__ __launch_bounds__(256) void bucket_mat_L1(
        const int* __restrict__ mrow, const int* __restrict__ mcol,
        int* __restrict__ stC, int* __restrict__ curC,
        int* __restrict__ stR, int* __restrict__ curR) {
    __shared__ int bufc[8][CAPB];
    __shared__ int bufr[8][CAPB];
    __shared__ int lc[8], lr[8], gc[8], gr[8];
    const int tid = threadIdx.x;
    const int lane = tid & 63;
    for (int cs = blockIdx.x * CHUNK; cs < NNI; cs += gridDim.x * CHUNK) {
        if (tid < 8) { lc[tid] = 0; lr[tid] = 0; }
        __syncthreads();
        const int ce = min(cs + CHUNK, NNI);
        for (int i0 = cs; i0 < ce; i0 += 256) {
            const int i = i0 + tid;
            const bool valid = i < ce;
            int r = 0, c = 0, bc = 8, br = 8;
            if (valid) {
                r = __builtin_nontemporal_load(mrow + i);
                c = __builtin_nontemporal_load(mcol + i);
                bc = c / PART_I;
                br = r / PART_I;
            }
            unsigned long long mc[8], mrr[8];
            #pragma unroll
            for (int k = 0; k < 8; ++k) { mc[k] = __ballot(bc == k); mrr[k] = __ballot(br == k); }
            int bc8 = 0, br8 = 0;
            if (lane < 8) {
                bc8 = atomicAdd(&lc[lane], (int)__popcll(mc[lane]));
                br8 = atomicAdd(&lr[lane], (int)__popcll(mrr[lane]));
            }
            if (valid) {
                const unsigned long long lt = (1ull << lane) - 1ull;
                int pos = __shfl(bc8, bc) + (int)__popcll(mc[bc] & lt);
                const int vc = (int)(((unsigned)c << 16) | (unsigned)r);
                if (pos < CAPB) bufc[bc][pos] = vc;
                else stC[(size_t)bc * ECAP_M + atomicAdd(&curC[bc], 1)] = vc;
                pos = __shfl(br8, br) + (int)__popcll(mrr[br] & lt);
                const int vr = (int)(((unsigned)r << 16) | (unsigned)c);
                if (pos < CAPB) bufr[br][pos] = vr;
                else stR[(size_t)br * ECAP_M + atomicAdd(&curR[br], 1)] = vr;
            }
        }
        __syncthreads();
        if (tid < 8)       gc[tid]     = atomicAdd(&curC[tid],     min(lc[tid],     CAPB));
        else if (tid < 16) gr[tid - 8] = atomicAdd(&curR[tid - 8], min(lr[tid - 8], CAPB));
        __syncthreads();
        for (int b = 0; b < 8; ++b) {
            int nf = min(lc[b], CAPB);
            int* d = stC + (size_t)b * ECAP_M + gc[b];
            for (int j = tid; j < nf; j += 256) d[j] = bufc[b][j];
            nf = min(lr[b], CAPB);
            d = stR + (size_t)b * ECAP_M + gr[b];
            for (int j = tid; j < nf; j += 256) d[j] = bufr[b][j];
        }
        __syncthreads();
    }
}

// ---------------------------------------------------------------------------
// L2 bucket: partition bucket -> groups of 125 rows.
// edge entry: (tail|etype<<17) | rowInGroup<<22.
// 1024 threads/block (16 waves) for latency hiding; grid stays 256.
// ---------------------------------------------------------------------------
__global__ __launch_bounds__(1024) void bucket_edge_L2(
        const int* __restrict__ stK, const int* __restrict__ stV,
        const int* __restrict__ cur, int* __restrict__ st2,
        int* __restrict__ cur2) {
    __shared__ int buf[NG_E][GCAP];
    __shared__ int lcnt[NG_E];
    const int p = blockIdx.x & 7;
    const int nb = gridDim.x >> 3;
    const int bi = blockIdx.x >> 3;
    const int n = cur[p];
    const int tid = threadIdx.x, w = tid >> 6, lane = tid & 63;
    const int* sK = stK + (size_t)p * ECAP_E;
    const int* sV = stV + (size_t)p * ECAP_E;
    const int pbase = p * PART_E;
    int* cur2p = cur2 + p * NG_E;
    for (int cs = bi * CHUNK; cs < n; cs += nb * CHUNK) {
        for (int t = tid; t < NG_E; t += 1024) lcnt[t] = 0;
        __syncthreads();
        const int ce = min(cs + CHUNK, n);
        for (int i = cs + tid; i < ce; i += 1024) {
            const int local = __builtin_nontemporal_load(sK + i) - pbase;
            const int g = local / GROUP;
            const int rig = local - g * GROUP;
            const int entry = __builtin_nontemporal_load(sV + i) | (rig << 22);
            const int pos = atomicAdd(&lcnt[g], 1);
            if (pos < GCAP) buf[g][pos] = entry;
            else st2[(size_t)(p * NG_E + g) * ST2CAP + atomicAdd(&cur2p[g], 1)] = entry;
        }
        __syncthreads();
        for (int gi = w; gi < NG_E; gi += 16) {
            const int nf = min(lcnt[gi], GCAP);
            int base = 0;
            if (lane == 0 && nf > 0) base = atomicAdd(&cur2p[gi], nf);
            base = __shfl(base, 0);
            int* d = st2 + (size_t)(p * NG_E + gi) * ST2CAP + base;
            for (int j = lane; j < nf; j += 64) d[j] = buf[gi][j];
        }
        __syncthreads();
    }
}

// mat entry: other | rowInGroup<<16.  (same 1024-thread config)
__global__ __launch_bounds__(1024) void bucket_mat_L2(
        const int* __restrict__ st, const int* __restrict__ cur8,
        int* __restrict__ st2, int* __restrict__ cur2) {
    __shared__ int buf[NG_M][GCAP];
    __shared__ int lcnt[NG_M];
    const int p = blockIdx.x & 7;
    const int nb = gridDim.x >> 3;
    const int bi = blockIdx.x >> 3;
    const int n = cur8[p];
    const int tid = threadIdx.x, w = tid >> 6, lane = tid & 63;
    const int* s = st + (size_t)p * ECAP_M;
    const int pbase = p * PART_I;
    int* cur2p = cur2 + p * NG_M;
    for (int cs = bi * CHUNK; cs < n; cs += nb * CHUNK) {
        for (int t = tid; t < NG_M; t += 1024) lcnt[t] = 0;
        __syncthreads();
        const int ce = min(cs + CHUNK, n);
        for (int i = cs + tid; i < ce; i += 1024) {
            const unsigned u = (unsigned)__builtin_nontemporal_load(s + i);
            const int local = (int)(u >> 16) - pbase;
            const int g = local / GROUP;
            const int rig = local - g * GROUP;
            const int entry = (int)(u & 0xFFFFu) | (rig << 16);
            const int pos = atomicAdd(&lcnt[g], 1);
            if (pos < GCAP) buf[g][pos] = entry;
            else st2[(size_t)(p * NG_M + g) * ST2CAP + atomicAdd(&cur2p[g], 1)] = entry;
        }
        __syncthreads();
        for (int gi = w; gi < NG_M; gi += 16) {
            const int nf = min(lcnt[gi], GCAP);
            int base = 0;
            if (lane == 0 && nf > 0) base = atomicAdd(&cur2p[gi], nf);
            base = __shfl(base, 0);
            int* d = st2 + (size_t)(p * NG_M + gi) * ST2CAP + base;
            for (int j = lane; j < nf; j += 64) d[j] = buf[gi][j];
        }
        __syncthreads();
    }
}

// ---------------------------------------------------------------------------
// Group-local LDS counting sort. Entries RETAIN their rig bits after sorting
// (consumers must mask). SHIFT: 22 for edges, 16 for mat.
// ---------------------------------------------------------------------------
template <int SHIFT>
__device__ __forceinline__ void group_sort_body(
        int* __restrict__ st2, const int* __restrict__ cur2, int gg,
        int* __restrict__ row_beg, int* __restrict__ row_cnt) {
    __shared__ int cnt[256];
    __shared__ int loc[GROUP];
    __shared__ int curs[GROUP];
    __shared__ int sorted[ST2CAP];
    const int tid = threadIdx.x;
    const int n = cur2[gg];
    int* s = st2 + (size_t)gg * ST2CAP;
    cnt[tid] = 0;
    __syncthreads();
    for (int i = tid; i < n; i += 256) atomicAdd(&cnt[s[i] >> SHIFT], 1);
    __syncthreads();
    const int x = cnt[tid];
    for (int d = 1; d < 256; d <<= 1) {
        const int v = (tid >= d) ? cnt[tid - d] : 0;
        __syncthreads();
        cnt[tid] += v;
        __syncthreads();
    }
    const int excl = cnt[tid] - x;
    if (tid < GROUP) { loc[tid] = excl; curs[tid] = excl; }
    __syncthreads();
    for (int i = tid; i < n; i += 256) {
        const int e = s[i];
        const int pos = atomicAdd(&curs[e >> SHIFT], 1);
        sorted[pos] = e;
    }
    __syncthreads();
    for (int i = tid; i < n; i += 256) s[i] = sorted[i];
    if (tid < GROUP) {
        row_beg[gg * GROUP + tid] = gg * ST2CAP + loc[tid];
        row_cnt[gg * GROUP + tid] = x;
    }
}

__global__ __launch_bounds__(256) void group_sort_e(
        int* __restrict__ st2, const int* __restrict__ cur2,
        int* __restrict__ row_beg, int* __restrict__ row_cnt) {
    group_sort_body<22>(st2, cur2, blockIdx.x, row_beg, row_cnt);
}

__global__ __launch_bounds__(256) void group_sort_m(
        int* __restrict__ stC2, const int* __restrict__ cur2c,
        int* __restrict__ begc, int* __restrict__ cntc,
        int* __restrict__ stR2, const int* __restrict__ cur2r,
        int* __restrict__ begr, int* __restrict__ cntr) {
    const int b = blockIdx.x;
    if (b < 8 * NG_M) group_sort_body<16>(stC2, cur2c, b, begc, cntc);
    else              group_sort_body<16>(stR2, cur2r, b - 8 * NG_M, begr, cntr);
}

// ---------------------------------------------------------------------------
// Pull aggregations. NOTE: mat entries carry rig<<16 — MASK with 0xFFFF
// (dropping this mask caused the round 9-11 device faults).
// ---------------------------------------------------------------------------
__global__ void pull_entity_kernel(const float* __restrict__ ent,
                                   const float* __restrict__ wgt,
                                   const int* __restrict__ row_beg,
                                   const int* __restrict__ row_cnt,
                                   const int* __restrict__ ids,
                                   float* __restrict__ out) {
    const int lane = threadIdx.x & 63;
    const int wid = (blockIdx.x * blockDim.x + threadIdx.x) >> 6;
    if (wid >= N_ENT) return;
    const int beg = row_beg[wid], nc = row_cnt[wid];
    const int end = beg + nc;
    float acc = 0.f;
    for (int base = beg; base < end; base += 64) {
        const int k = base + lane;
        int v = 0;
        if (k < end) v = ids[k];
        const int nn = min(64, end - base);
        int kk = 0;
        for (; kk + 4 <= nn; kk += 4) {
            const int v0 = __shfl(v, kk),     v1 = __shfl(v, kk + 1);
            const int v2 = __shfl(v, kk + 2), v3 = __shfl(v, kk + 3);
            const float a0 = ent[(size_t)(v0 & 0x1FFFF) * DD + lane] * wgt[((v0 >> 17) & 31) * DD + lane];
            const float a1 = ent[(size_t)(v1 & 0x1FFFF) * DD + lane] * wgt[((v1 >> 17) & 31) * DD + lane];
            const float a2 = ent[(size_t)(v2 & 0x1FFFF) * DD + lane] * wgt[((v2 >> 17) & 31) * DD + lane];
            const float a3 = ent[(size_t)(v3 & 0x1FFFF) * DD + lane] * wgt[((v3 >> 17) & 31) * DD + lane];
            acc += a0 + a1 + a2 + a3;
        }
        for (; kk < nn; ++kk) {
            const int vv = __shfl(v, kk);
            acc += ent[(size_t)(vv & 0x1FFFF) * DD + lane] * wgt[((vv >> 17) & 31) * DD + lane];
        }
    }
    out[(size_t)wid * DD + lane] = acc / fmaxf((float)nc, 1.0f);
}

__global__ void pull_iu_kernel(const float* __restrict__ uemb,
                               const float* __restrict__ wgt,
                               const int* __restrict__ row_beg,
                               const int* __restrict__ row_cnt,
                               const int* __restrict__ ids,
                               float* __restrict__ iu_out) {
    const int lane = threadIdx.x & 63;
    const int wid = (blockIdx.x * blockDim.x + threadIdx.x) >> 6;
    if (wid >= N_ITEMS) return;
    const float w0 = wgt[lane];
    const int beg = row_beg[wid], nc = row_cnt[wid];
    const int end = beg + nc;
    float acc = 0.f;
    for (int base = beg; base < end; base += 64) {
        const int k = base + lane;
        int v = 0;
        if (k < end) v = ids[k];
        const int nn = min(64, end - base);
        int kk = 0;
        for (; kk + 4 <= nn; kk += 4) {
            const int v0 = __shfl(v, kk),     v1 = __shfl(v, kk + 1);
            const int v2 = __shfl(v, kk + 2), v3 = __shfl(v, kk + 3);
            acc += uemb[(size_t)(v0 & 0xFFFF) * DD + lane] + uemb[(size_t)(v1 & 0xFFFF) * DD + lane]
                 + uemb[(size_t)(v2 & 0xFFFF) * DD + lane] + uemb[(size_t)(v3 & 0xFFFF) * DD + lane];
        }
        for (; kk < nn; ++kk) {
            const int vv = __shfl(v, kk);
            acc += uemb[(size_t)(vv & 0xFFFF) * DD + lane];
        }
    }
    iu_out[(size_t)wid * DD + lane] = acc * w0 / fmaxf((float)nc, 1.0f);
}

__global__ void pull_user_kernel(const float* __restrict__ fus,
                                 const int* __restrict__ row_beg,
                                 const int* __restrict__ row_cnt,
                                 const int* __restrict__ ids,
                                 float* __restrict__ uout) {
    const int lane = threadIdx.x & 63;
    const int wid = (blockIdx.x * blockDim.x + threadIdx.x) >> 6;
    if (wid >= N_USERS) return;
    const int beg = row_beg[wid], nc = row_cnt[wid];
    const int end = beg + nc;
    float acc = 0.f;
    for (int base = beg; base < end; base += 64) {
        const int k = base + lane;
        int v = 0;
        if (k < end) v = ids[k];
        const int nn = min(64, end - base);
        int kk = 0;
        for (; kk + 4 <= nn; kk += 4) {
            const int v0 = __shfl(v, kk),     v1 = __shfl(v, kk + 1);
            const int v2 = __shfl(v, kk + 2), v3 = __shfl(v, kk + 3);
            acc += fus[(size_t)(v0 & 0xFFFF) * DD + lane] + fus[(size_t)(v1 & 0xFFFF) * DD + lane]
                 + fus[(size_t)(v2 & 0xFFFF) * DD + lane] + fus[(size_t)(v3 & 0xFFFF) * DD + lane];
        }
        for (; kk < nn; ++kk) {
            const int vv = __shfl(v, kk);
            acc += fus[(size_t)(vv & 0xFFFF) * DD + lane];
        }
    }
    uout[(size_t)wid * DD + lane] = acc;
}

// ---------------------------------------------------------------------------
// Gate + fusion, in place on d_out. 4 items / 256-thread block.
// ---------------------------------------------------------------------------
__global__ void gate_fusion_kernel(float* __restrict__ kg_fus,
                                   const float* __restrict__ iu,
                                   const float* __restrict__ g1,
                                   const float* __restrict__ g2) {
    __shared__ float G1[64 * 65];
    __shared__ float G2[64 * 65];
    __shared__ float xs1[4][64];
    __shared__ float xs2[4][64];

    const int tid = threadIdx.x;
    for (int i = tid; i < 64 * 64; i += 256) {
        const int r = i >> 6, c = i & 63;
        G1[r * 65 + c] = g1[i];
        G2[r * 65 + c] = g2[i];
    }

    const int il = tid >> 6;
    const int j = tid & 63;
    const int item = blockIdx.x * 4 + il;

    const float x1 = kg_fus[(size_t)item * DD + j];
    const float x2 = iu[(size_t)item * DD + j];
    xs1[il][j] = x1;
    xs2[il][j] = x2;
    __syncthreads();

    float s = 0.0f;
    #pragma unroll
    for (int k = 0; k < 64; ++k) {
        s += xs1[il][k] * G1[j * 65 + k];
        s += xs2[il][k] * G2[j * 65 + k];
    }
    const float gi = 1.0f / (1.0f + __expf(-s));
    kg_fus[(size_t)item * DD + j] = gi * x1 + (1.0f - gi) * x2;
}

extern "C" void kernel_launch(void* const* d_in, const int* in_sizes, int n_in,
                              void* d_out, int out_size, void* d_ws, size_t ws_size,
                              hipStream_t stream) {
    const float* entity_emb = (const float*)d_in[0];
    const float* user_emb   = (const float*)d_in[1];
    const int*   edge_index = (const int*)d_in[2];
    const int*   edge_type  = (const int*)d_in[3];
    const int*   mat_row    = (const int*)d_in[4];
    const int*   mat_col    = (const int*)d_in[5];
    const float* weight     = (const float*)d_in[7];
    const float* gate1_w    = (const float*)d_in[8];
    const float* gate2_w    = (const float*)d_in[9];

    float* out = (float*)d_out;
    float* out_fusion = out;                       // rows [0, 50000)
    float* out_entity = out;                       // rows [0, 100000)
    float* out_user   = out + (size_t)N_ENT * DD;  // temp i_u_agg, then user_agg

    // workspace (ints), ~27.6 MB, phase-ordered aliasing:
    //  A: st_ek -> later stC|stR (after group_sort_e)
    //  B: st_ev -> later stC2    (after group_sort_e)
    //  C: st2_e -> later stR2    (after pull_entity)
    int* W      = (int*)d_ws;
    int* cur_e  = W + 0;         // 8
    int* cur_c  = W + 8;         // 8
    int* cur_r  = W + 16;        // 8
    int* cur2_e = W + 24;        // 800
    int* cur2_c = W + 824;       // 400
    int* cur2_r = W + 1224;      // 400   (cursors end 1624, pad to 2048)
    int* st_ek  = W + 2048;                    // 2,097,152
    int* st_ev  = W + 2048 + 2097152;          // 2,097,152
    int* st2_e  = W + 2048 + 2 * 2097152;      // 800*2880 = 2,304,000
    int* stC    = st_ek;                       // 1,048,576 (aliases A)
    int* stR    = st_ek + 1048576;             // 1,048,576 (aliases A)
    int* stC2   = st_ev;                       // 400*2880 = 1,152,000 (aliases B)
    int* stR2   = st2_e;                       // 1,152,000 (aliases C)
    int* tabs   = W + 2048 + 2 * 2097152 + 2304000;
    int* beg_e  = tabs;            // 100,000
    int* cnt_e  = tabs + 100000;   // 100,000
    int* beg_c  = tabs + 200000;   // 50,000
    int* cnt_c  = tabs + 250000;   // 50,000
    int* beg_r  = tabs + 300000;   // 50,000
    int* cnt_r  = tabs + 350000;   // 50,000  (end = 6,900,352 ints ~ 27.6 MB)

    const int* head = edge_index;
    const int* tail = edge_index + NE;

    // zero all cursors (8 KB)
    (void)hipMemsetAsync(W, 0, 2048 * sizeof(int), stream);

    // ---- entity chain ----
    bucket_edge_L1<<<512, 256, 0, stream>>>(head, tail, edge_type, st_ek, st_ev, cur_e);
    bucket_edge_L2<<<256, 1024, 0, stream>>>(st_ek, st_ev, cur_e, st2_e, cur2_e);
    group_sort_e<<<800, 256, 0, stream>>>(st2_e, cur2_e, beg_e, cnt_e);
    pull_entity_kernel<<<N_ENT / 4, 256, 0, stream>>>(entity_emb, weight,
                                                      beg_e, cnt_e, st2_e, out_entity);

    // ---- mat chains (regions A/B/C recycled; after pull_entity) ----
    bucket_mat_L1<<<256, 256, 0, stream>>>(mat_row, mat_col, stC, cur_c, stR, cur_r);
    bucket_mat_L2<<<256, 1024, 0, stream>>>(stC, cur_c, stC2, cur2_c);
    bucket_mat_L2<<<256, 1024, 0, stream>>>(stR, cur_r, stR2, cur2_r);
    group_sort_m<<<800, 256, 0, stream>>>(stC2, cur2_c, beg_c, cnt_c,
                                          stR2, cur2_r, beg_r, cnt_r);
    pull_iu_kernel<<<N_ITEMS / 4, 256, 0, stream>>>(user_emb, weight,
                                                    beg_c, cnt_c, stC2, out_user);

    // ---- gate + fusion (in place on d_out item rows) ----
    gate_fusion_kernel<<<N_ITEMS / 4, 256, 0, stream>>>(out_fusion, out_user,
                                                        gate1_w, gate2_w);

    // ---- user_agg ----
    pull_user_kernel<<<N_USERS / 4, 256, 0, stream>>>(out_fusion,
                                                      beg_r, cnt_r, stR2, out_user);
}